// Round 1
// 312.914 us; speedup vs baseline: 1.1461x; 1.1461x over previous
//
#include <hip/hip_runtime.h>

#define THREADS 256
#define KC 32
#define B1 256          // partition blocks for P1/P2 (edge chunks)

// ---- bf16 helpers ----
__device__ inline ushort f2bf(float v) {
    union { float f; unsigned u; } a; a.f = v;
    unsigned r = a.u + 0x7fff + ((a.u >> 16) & 1);
    return (ushort)(r >> 16);
}
__device__ inline unsigned pack2(float a, float b) {
    return (unsigned)f2bf(a) | ((unsigned)f2bf(b) << 16);
}
__device__ inline float bflo(unsigned v) {
    union { unsigned u; float f; } a; a.u = v << 16; return a.f;
}
__device__ inline float bfhi(unsigned v) {
    union { unsigned u; float f; } a; a.u = v & 0xffff0000u; return a.f;
}

// =================== CSR build: LDS counting sort, zero global atomics =======

// ---- P1: per-chunk bucket histogram (bucket = dst>>8, NB buckets) ----
__global__ void k_p1(const int* __restrict__ dst, int* __restrict__ pc,
                     int E, int NB, int chunk) {
    __shared__ int hist[512];
    int tid = threadIdx.x, blk = blockIdx.x;
    for (int i = tid; i < NB; i += THREADS) hist[i] = 0;
    __syncthreads();
    int e0 = blk * chunk;
    int e1 = e0 + chunk; if (e1 > E) e1 = E;
    for (int e = e0 + tid; e < e1; e += THREADS)
        atomicAdd(&hist[dst[e] >> 8], 1);
    __syncthreads();
    for (int i = tid; i < NB; i += THREADS) pc[i * B1 + blk] = hist[i];
}

// ---- s1: block-local exclusive scan of pc (1024/block) + block totals ----
__global__ void k_s1(int* __restrict__ pc, int* __restrict__ bsums, int total) {
    __shared__ int s[1024];
    int t = threadIdx.x;
    int idx = blockIdx.x * 1024 + t;
    int v = (idx < total) ? pc[idx] : 0;
    s[t] = v;
    __syncthreads();
    for (int o = 1; o < 1024; o <<= 1) {
        int x = (t >= (unsigned)o) ? s[t - o] : 0;
        __syncthreads();
        s[t] += x;
        __syncthreads();
    }
    if (idx < total) pc[idx] = s[t] - v;           // exclusive within block
    if (t == 1023) bsums[blockIdx.x] = s[1023];    // block total
}

// ---- s2: exclusive scan of block totals in place (nb <= 128) ----
__global__ void k_s2(int* __restrict__ bsums, int nb) {
    __shared__ int s[128];
    int t = threadIdx.x;
    int v = (t < nb) ? bsums[t] : 0;
    s[t] = v;
    __syncthreads();
    for (int o = 1; o < 128; o <<= 1) {
        int x = (t >= (unsigned)o) ? s[t - o] : 0;
        __syncthreads();
        s[t] += x;
        __syncthreads();
    }
    if (t < nb) bsums[t] = s[t] - v;
}

// global exclusive base for flat index i: pc[i] + bsums[i>>10]

// ---- P2: partition (src,dst) pairs into part[] grouped by bucket ----
__global__ void k_p2(const int* __restrict__ src, const int* __restrict__ dst,
                     const int* __restrict__ pc, const int* __restrict__ bsx,
                     unsigned long long* __restrict__ part, int E, int NB, int chunk) {
    __shared__ int cur[512];
    int tid = threadIdx.x, blk = blockIdx.x;
    for (int i = tid; i < NB; i += THREADS) {
        int idx = i * B1 + blk;
        cur[i] = pc[idx] + bsx[idx >> 10];
    }
    __syncthreads();
    int e0 = blk * chunk;
    int e1 = e0 + chunk; if (e1 > E) e1 = E;
    for (int e = e0 + tid; e < e1; e += THREADS) {
        int d = dst[e], sv = src[e];
        int pos = atomicAdd(&cur[d >> 8], 1);      // LDS atomic
        part[pos] = ((unsigned long long)(unsigned)d << 32) | (unsigned)sv;
    }
}

// ---- P3: per-bucket (256 nodes) LDS counting sort -> off, dinv, csr ----
__global__ void k_p3(const unsigned long long* __restrict__ part,
                     const int* __restrict__ pc, const int* __restrict__ bsx,
                     int* __restrict__ off, float* __restrict__ dinv,
                     int* __restrict__ csr, int E, int NB, int n) {
    __shared__ int hist[256];
    __shared__ int so[256];
    int b = blockIdx.x, t = threadIdx.x;
    int i0 = b * B1, i1 = (b + 1) * B1;
    int base = pc[i0] + bsx[i0 >> 10];
    int end  = (b + 1 < NB) ? (pc[i1] + bsx[i1 >> 10]) : E;
    hist[t] = 0;
    __syncthreads();
    for (int e = base + t; e < end; e += THREADS)
        atomicAdd(&hist[(int)(part[e] >> 32) & 255], 1);
    __syncthreads();
    int h = hist[t];
    so[t] = h;
    __syncthreads();
    for (int o = 1; o < 256; o <<= 1) {
        int x = (t >= (unsigned)o) ? so[t - o] : 0;
        __syncthreads();
        so[t] += x;
        __syncthreads();
    }
    int ex = so[t] - h;                            // exclusive within bucket
    int node = (b << 8) + t;
    if (node < n) {
        off[node]  = base + ex;
        dinv[node] = rsqrtf((float)h + 1.0f);
        if (node == n - 1) off[n] = E;
    }
    __syncthreads();
    so[t] = base + ex;                             // cursors
    __syncthreads();
    for (int e = base + t; e < end; e += THREADS) {
        unsigned long long p = part[e];
        int pos = atomicAdd(&so[(int)(p >> 32) & 255], 1);   // LDS atomic
        csr[pos] = (int)(p & 0xffffffffu);
    }
}

// =================== GEMM1 (fp32 X, dinv epilogue) + fused cnt role ========
__global__ __launch_bounds__(THREADS) void
k_g1(const float* __restrict__ X, const float* __restrict__ W,
     const float* __restrict__ dinv, ushort* __restrict__ C, int n, int fin,
     const int* __restrict__ dict, float* __restrict__ cnt, int nGemm, int nCnt) {
    int tid = threadIdx.x;
    if ((int)blockIdx.x >= nGemm) {
        // ---- cnt role: dict histogram (100K atomics, hidden under GEMM) ----
        int stride = nCnt * THREADS;
        for (int i = ((int)blockIdx.x - nGemm) * THREADS + tid; i < n; i += stride)
            atomicAdd(&cnt[dict[i]], 1.0f);
        return;
    }
    __shared__ float Xs[KC][68];
    __shared__ float Ws[KC][64];
    int r0  = blockIdx.x * 64;
    int tx4 = (tid & 15) * 4;
    int ty4 = (tid >> 4) * 4;
    int sxr = tid >> 2, sxk = (tid & 3) * 4;
    int swk = tid >> 4, swc = (tid & 15) * 4;
    int xrow = r0 + sxr; if (xrow >= n) xrow = n - 1;
    const float* xptr = X + (size_t)xrow * fin;
    float4 acc0 = {0,0,0,0}, acc1 = {0,0,0,0}, acc2 = {0,0,0,0}, acc3 = {0,0,0,0};
    for (int kc = 0; kc < fin; kc += KC) {
        float4 xa = *(const float4*)(xptr + kc + sxk);
        float4 xb = *(const float4*)(xptr + kc + 16 + sxk);
        float4 wa = *(const float4*)(W + (size_t)(kc + swk) * 64 + swc);
        float4 wb = *(const float4*)(W + (size_t)(kc + swk + 16) * 64 + swc);
        __syncthreads();
        Xs[sxk + 0][sxr] = xa.x; Xs[sxk + 1][sxr] = xa.y;
        Xs[sxk + 2][sxr] = xa.z; Xs[sxk + 3][sxr] = xa.w;
        Xs[16 + sxk + 0][sxr] = xb.x; Xs[16 + sxk + 1][sxr] = xb.y;
        Xs[16 + sxk + 2][sxr] = xb.z; Xs[16 + sxk + 3][sxr] = xb.w;
        *(float4*)&Ws[swk][swc]      = wa;
        *(float4*)&Ws[swk + 16][swc] = wb;
        __syncthreads();
        #pragma unroll 8
        for (int k = 0; k < KC; ++k) {
            float4 a = *(const float4*)&Xs[k][ty4];
            float4 b = *(const float4*)&Ws[k][tx4];
            acc0.x = fmaf(a.x, b.x, acc0.x); acc0.y = fmaf(a.x, b.y, acc0.y);
            acc0.z = fmaf(a.x, b.z, acc0.z); acc0.w = fmaf(a.x, b.w, acc0.w);
            acc1.x = fmaf(a.y, b.x, acc1.x); acc1.y = fmaf(a.y, b.y, acc1.y);
            acc1.z = fmaf(a.y, b.z, acc1.z); acc1.w = fmaf(a.y, b.w, acc1.w);
            acc2.x = fmaf(a.z, b.x, acc2.x); acc2.y = fmaf(a.z, b.y, acc2.y);
            acc2.z = fmaf(a.z, b.z, acc2.z); acc2.w = fmaf(a.z, b.w, acc2.w);
            acc3.x = fmaf(a.w, b.x, acc3.x); acc3.y = fmaf(a.w, b.y, acc3.y);
            acc3.z = fmaf(a.w, b.z, acc3.z); acc3.w = fmaf(a.w, b.w, acc3.w);
        }
    }
    int row = r0 + ty4;
    #pragma unroll
    for (int r = 0; r < 4; ++r) {
        if (row + r >= n) break;
        float dn = dinv[row + r];
        float4 a = r == 0 ? acc0 : r == 1 ? acc1 : r == 2 ? acc2 : acc3;
        ushort4 o;
        o.x = f2bf(a.x * dn); o.y = f2bf(a.y * dn);
        o.z = f2bf(a.z * dn); o.w = f2bf(a.w * dn);
        *(ushort4*)(C + (size_t)(row + r) * 64 + tx4) = o;
    }
}

// ---------- tiled GEMM (bf16 X): C' = (X@W)*dinv -> bf16 ----------
__global__ __launch_bounds__(THREADS) void
k_gemm_bf16(const ushort* __restrict__ X, const float* __restrict__ W,
            const float* __restrict__ dinv, ushort* __restrict__ C, int n, int fin) {
    __shared__ float Xs[KC][68];
    __shared__ float Ws[KC][64];
    int tid = threadIdx.x;
    int r0  = blockIdx.x * 64;
    int tx4 = (tid & 15) * 4;
    int ty4 = (tid >> 4) * 4;
    int sxr = tid >> 2, sk8 = (tid & 3) * 8;
    int swk = tid >> 4, swc = (tid & 15) * 4;
    int xrow = r0 + sxr; if (xrow >= n) xrow = n - 1;
    const ushort* xptr = X + (size_t)xrow * fin;
    float4 acc0 = {0,0,0,0}, acc1 = {0,0,0,0}, acc2 = {0,0,0,0}, acc3 = {0,0,0,0};
    for (int kc = 0; kc < fin; kc += KC) {
        uint4 xv = *(const uint4*)(xptr + kc + sk8);
        float4 wa = *(const float4*)(W + (size_t)(kc + swk) * 64 + swc);
        float4 wb = *(const float4*)(W + (size_t)(kc + swk + 16) * 64 + swc);
        __syncthreads();
        Xs[sk8 + 0][sxr] = bflo(xv.x); Xs[sk8 + 1][sxr] = bfhi(xv.x);
        Xs[sk8 + 2][sxr] = bflo(xv.y); Xs[sk8 + 3][sxr] = bfhi(xv.y);
        Xs[sk8 + 4][sxr] = bflo(xv.z); Xs[sk8 + 5][sxr] = bfhi(xv.z);
        Xs[sk8 + 6][sxr] = bflo(xv.w); Xs[sk8 + 7][sxr] = bfhi(xv.w);
        *(float4*)&Ws[swk][swc]      = wa;
        *(float4*)&Ws[swk + 16][swc] = wb;
        __syncthreads();
        #pragma unroll 8
        for (int k = 0; k < KC; ++k) {
            float4 a = *(const float4*)&Xs[k][ty4];
            float4 b = *(const float4*)&Ws[k][tx4];
            acc0.x = fmaf(a.x, b.x, acc0.x); acc0.y = fmaf(a.x, b.y, acc0.y);
            acc0.z = fmaf(a.x, b.z, acc0.z); acc0.w = fmaf(a.x, b.w, acc0.w);
            acc1.x = fmaf(a.y, b.x, acc1.x); acc1.y = fmaf(a.y, b.y, acc1.y);
            acc1.z = fmaf(a.y, b.z, acc1.z); acc1.w = fmaf(a.y, b.w, acc1.w);
            acc2.x = fmaf(a.z, b.x, acc2.x); acc2.y = fmaf(a.z, b.y, acc2.y);
            acc2.z = fmaf(a.z, b.z, acc2.z); acc2.w = fmaf(a.z, b.w, acc2.w);
            acc3.x = fmaf(a.w, b.x, acc3.x); acc3.y = fmaf(a.w, b.y, acc3.y);
            acc3.z = fmaf(a.w, b.z, acc3.z); acc3.w = fmaf(a.w, b.w, acc3.w);
        }
    }
    int row = r0 + ty4;
    #pragma unroll
    for (int r = 0; r < 4; ++r) {
        if (row + r >= n) break;
        float dn = dinv[row + r];
        float4 a = r == 0 ? acc0 : r == 1 ? acc1 : r == 2 ? acc2 : acc3;
        ushort4 o;
        o.x = f2bf(a.x * dn); o.y = f2bf(a.y * dn);
        o.z = f2bf(a.z * dn); o.w = f2bf(a.w * dn);
        *(ushort4*)(C + (size_t)(row + r) * 64 + tx4) = o;
    }
}

// ---------- MLP gather core: wave = 1 node, 8 rows per mem instruction ----------
__device__ inline void gather_sum8(const ushort* __restrict__ H,
                                   const int* __restrict__ csr,
                                   int node, int j, int end, int g, int q,
                                   float4& R0, float4& R1) {
    float4 A0 = {0,0,0,0}, B0 = {0,0,0,0}, A1 = {0,0,0,0}, B1v = {0,0,0,0};
    if (g == 0) {  // self row joins slot 0
        uint4 sv = *(const uint4*)(H + ((size_t)node << 6) + q * 8);
        A0.x += bflo(sv.x); A0.y += bfhi(sv.x); A0.z += bflo(sv.y); A0.w += bfhi(sv.y);
        B0.x += bflo(sv.z); B0.y += bfhi(sv.z); B0.z += bflo(sv.w); B0.w += bfhi(sv.w);
    }
    for (; j + 16 <= end; j += 16) {
        int s0 = csr[j + g];
        int s1 = csr[j + 8 + g];
        uint4 v0 = *(const uint4*)(H + ((size_t)s0 << 6) + q * 8);
        uint4 v1 = *(const uint4*)(H + ((size_t)s1 << 6) + q * 8);
        A0.x += bflo(v0.x); A0.y += bfhi(v0.x); A0.z += bflo(v0.y); A0.w += bfhi(v0.y);
        B0.x += bflo(v0.z); B0.y += bfhi(v0.z); B0.z += bflo(v0.w); B0.w += bfhi(v0.w);
        A1.x += bflo(v1.x); A1.y += bfhi(v1.x); A1.z += bflo(v1.y); A1.w += bfhi(v1.y);
        B1v.x += bflo(v1.z); B1v.y += bfhi(v1.z); B1v.z += bflo(v1.w); B1v.w += bfhi(v1.w);
    }
    if (j + 8 <= end) {
        int s0 = csr[j + g];
        uint4 v0 = *(const uint4*)(H + ((size_t)s0 << 6) + q * 8);
        A0.x += bflo(v0.x); A0.y += bfhi(v0.x); A0.z += bflo(v0.y); A0.w += bfhi(v0.y);
        B0.x += bflo(v0.z); B0.y += bfhi(v0.z); B0.z += bflo(v0.w); B0.w += bfhi(v0.w);
        j += 8;
    }
    if (g < end - j) {
        int s1 = csr[j + g];
        uint4 v1 = *(const uint4*)(H + ((size_t)s1 << 6) + q * 8);
        A1.x += bflo(v1.x); A1.y += bfhi(v1.x); A1.z += bflo(v1.y); A1.w += bfhi(v1.y);
        B1v.x += bflo(v1.z); B1v.y += bfhi(v1.z); B1v.z += bflo(v1.w); B1v.w += bfhi(v1.w);
    }
    R0.x = A0.x + A1.x; R0.y = A0.y + A1.y; R0.z = A0.z + A1.z; R0.w = A0.w + A1.w;
    R1.x = B0.x + B1v.x; R1.y = B0.y + B1v.y; R1.z = B0.z + B1v.z; R1.w = B0.w + B1v.w;
    #pragma unroll
    for (int o = 8; o <= 32; o <<= 1) {
        R0.x += __shfl_xor(R0.x, o); R0.y += __shfl_xor(R0.y, o);
        R0.z += __shfl_xor(R0.z, o); R0.w += __shfl_xor(R0.w, o);
        R1.x += __shfl_xor(R1.x, o); R1.y += __shfl_xor(R1.y, o);
        R1.z += __shfl_xor(R1.z, o); R1.w += __shfl_xor(R1.w, o);
    }
}

// ---------- layer-1: gather + self + bias + ReLU -> bf16 ----------
__global__ void k_gcn_gather(const ushort* __restrict__ H, const int* __restrict__ csr,
                             const int* __restrict__ off, const float* __restrict__ dinv,
                             const float* __restrict__ b, ushort* __restrict__ out, int n) {
    int t = blockIdx.x * blockDim.x + threadIdx.x;
    int node = t >> 6;
    if (node >= n) return;
    int lane = threadIdx.x & 63;
    int g = lane >> 3, q = lane & 7;
    float4 R0, R1;
    gather_sum8(H, csr, node, off[node], off[node + 1], g, q, R0, R1);
    if (g == 0) {
        float dn = dinv[node];
        float4 b0 = *(const float4*)(b + q * 8);
        float4 b1 = *(const float4*)(b + q * 8 + 4);
        float v0 = R0.x * dn + b0.x, v1 = R0.y * dn + b0.y;
        float v2 = R0.z * dn + b0.z, v3 = R0.w * dn + b0.w;
        float v4 = R1.x * dn + b1.x, v5 = R1.y * dn + b1.y;
        float v6 = R1.z * dn + b1.z, v7 = R1.w * dn + b1.w;
        uint4 o;
        o.x = pack2(v0 > 0.f ? v0 : 0.f, v1 > 0.f ? v1 : 0.f);
        o.y = pack2(v2 > 0.f ? v2 : 0.f, v3 > 0.f ? v3 : 0.f);
        o.z = pack2(v4 > 0.f ? v4 : 0.f, v5 > 0.f ? v5 : 0.f);
        o.w = pack2(v6 > 0.f ? v6 : 0.f, v7 > 0.f ? v7 : 0.f);
        *(uint4*)(out + ((size_t)node << 6) + q * 8) = o;
    }
}

// ---------- layer-2: gather + ReLU + fused FC(64->16) + 16-dim pool scatter ----
__global__ void k_gcn_gather_fc(const ushort* __restrict__ H, const int* __restrict__ csr,
                                const int* __restrict__ off, const float* __restrict__ dinv,
                                const float* __restrict__ b, const float* __restrict__ Wfc,
                                const int* __restrict__ dict, float* __restrict__ pool16,
                                int n) {
    __shared__ float wt[16 * 65];
    __shared__ float hrow[4][64];
    int tid = threadIdx.x;
    for (int i = tid; i < 64 * 16; i += THREADS) {
        int cc = i >> 4, r = i & 15;
        wt[r * 65 + cc] = Wfc[i];
    }
    __syncthreads();
    int t = blockIdx.x * blockDim.x + tid;
    int node = t >> 6;
    int lane = tid & 63;
    int g = lane >> 3, q = lane & 7;
    int nl = tid >> 6;
    if (node < n) {
        float4 R0, R1;
        gather_sum8(H, csr, node, off[node], off[node + 1], g, q, R0, R1);
        if (g == 0) {
            float dn = dinv[node];
            float4 b0 = *(const float4*)(b + q * 8);
            float4 b1 = *(const float4*)(b + q * 8 + 4);
            float4 v0, v1;
            v0.x = R0.x * dn + b0.x; v0.y = R0.y * dn + b0.y;
            v0.z = R0.z * dn + b0.z; v0.w = R0.w * dn + b0.w;
            v1.x = R1.x * dn + b1.x; v1.y = R1.y * dn + b1.y;
            v1.z = R1.z * dn + b1.z; v1.w = R1.w * dn + b1.w;
            v0.x = v0.x > 0.f ? v0.x : 0.f; v0.y = v0.y > 0.f ? v0.y : 0.f;
            v0.z = v0.z > 0.f ? v0.z : 0.f; v0.w = v0.w > 0.f ? v0.w : 0.f;
            v1.x = v1.x > 0.f ? v1.x : 0.f; v1.y = v1.y > 0.f ? v1.y : 0.f;
            v1.z = v1.z > 0.f ? v1.z : 0.f; v1.w = v1.w > 0.f ? v1.w : 0.f;
            *(float4*)&hrow[nl][q * 8]     = v0;
            *(float4*)&hrow[nl][q * 8 + 4] = v1;
        }
        int g2 = lane >> 4, r = lane & 15;
        float p = 0.f;
        #pragma unroll
        for (int i = 0; i < 16; ++i) {
            int cc = g2 * 16 + i;
            p = fmaf(hrow[nl][cc], wt[r * 65 + cc], p);
        }
        p += __shfl_xor(p, 16);
        p += __shfl_xor(p, 32);
        if (g2 == 0)
            atomicAdd(&pool16[(size_t)dict[node] * 16 + r], p);
    }
}

// ---------- mean + bias + log_softmax over 16 classes ----------
__global__ void k_final16(const float* __restrict__ pool16, const float* __restrict__ cnt,
                          const float* __restrict__ bfc, float* __restrict__ out, int n) {
    int tid = threadIdx.x;
    int nl = tid >> 4, lane = tid & 15;
    int node = blockIdx.x * 16 + nl;
    if (node >= n) return;
    float inv = 1.0f / fmaxf(cnt[node], 1.0f);
    float acc = pool16[(size_t)node * 16 + lane] * inv + bfc[lane];
    float m = acc;
    for (int o = 8; o; o >>= 1) m = fmaxf(m, __shfl_xor(m, o, 16));
    float ex = __expf(acc - m);
    float s = ex;
    for (int o = 8; o; o >>= 1) s += __shfl_xor(s, o, 16);
    out[(size_t)node * 16 + lane] = acc - m - __logf(s);
}

extern "C" void kernel_launch(void* const* d_in, const int* in_sizes, int n_in,
                              void* d_out, int out_size, void* d_ws, size_t ws_size,
                              hipStream_t stream) {
    const float* x    = (const float*)d_in[0];
    const int*   ei   = (const int*)d_in[1];
    const int*   dict = (const int*)d_in[2];
    const float* W1   = (const float*)d_in[3];
    const float* b1   = (const float*)d_in[4];
    const float* W2   = (const float*)d_in[5];
    const float* b2   = (const float*)d_in[6];
    const float* Wfc  = (const float*)d_in[7];
    const float* bfc  = (const float*)d_in[8];

    const int N  = in_sizes[2];          // 100000
    const int E  = in_sizes[1] / 2;      // 1600000
    const int IN = in_sizes[0] / N;      // 128
    const int* src = ei;
    const int* dst = ei + E;

    // workspace layout (~40 MB)
    ushort* bufA = (ushort*)d_ws;                        // N*64 bf16
    ushort* bufB = bufA + (size_t)N * 64;                // N*64 bf16
    unsigned long long* part = (unsigned long long*)bufB;  // E u64 (alias bufB, dead before gather1)
    float* dinv    = (float*)(bufB + (size_t)N * 64);    // N
    float* cnt     = dinv + N;                           // N
    int*   off     = (int*)(cnt + N);                    // N+1
    int*   pcounts = off + (N + 1);                      // NB*B1
    const int NB     = (N + 255) >> 8;                   // 391 buckets of 256 nodes
    const int pcsize = NB * B1;                          // 100096
    int*   bsums   = pcounts + pcsize;                   // 128
    int*   csr     = bsums + 128;                        // E
    float* pool16  = (float*)(csr + E);                  // N*16

    const int gNE   = (N * 64 + THREADS - 1) / THREADS;  // 25000
    const int gTile = (N + 63) / 64;                     // 1563
    const int gRows = (N + 15) / 16;                     // 6250
    const int nCnt  = 256;
    const int chunk = (E + B1 - 1) / B1;                 // 6250
    const int nS1   = (pcsize + 1023) >> 10;             // 98

    hipMemsetAsync(cnt, 0, (size_t)N * sizeof(float), stream);
    hipMemsetAsync(pool16, 0, (size_t)N * 16 * sizeof(float), stream);

    // CSR build: LDS counting sort (no global atomics)
    k_p1<<<B1, THREADS, 0, stream>>>(dst, pcounts, E, NB, chunk);
    k_s1<<<nS1, 1024, 0, stream>>>(pcounts, bsums, pcsize);
    k_s2<<<1, 128, 0, stream>>>(bsums, nS1);
    k_p2<<<B1, THREADS, 0, stream>>>(src, dst, pcounts, bsums, part, E, NB, chunk);
    k_p3<<<NB, THREADS, 0, stream>>>(part, pcounts, bsums, off, dinv, csr, E, NB, N);

    // GEMM1 with dinv epilogue (+ dict cnt histogram hidden under it)
    k_g1<<<gTile + nCnt, THREADS, 0, stream>>>(x, W1, dinv, bufA, N, IN,
                                               dict, cnt, gTile, nCnt);

    // layer 1 gather: B = bf16(relu(dn*(sum+self)+b1))   (overwrites part alias)
    k_gcn_gather<<<gNE, THREADS, 0, stream>>>(bufA, csr, off, dinv, b1, bufB, N);

    // layer 2: A = bf16((B@W2)*dinv) ; fused gather+ReLU+FC+pool
    k_gemm_bf16<<<gTile, THREADS, 0, stream>>>(bufB, W2, dinv, bufA, N, 64);
    k_gcn_gather_fc<<<gNE, THREADS, 0, stream>>>(bufA, csr, off, dinv, b2, Wfc,
                                                 dict, pool16, N);

    // mean + bias + log_softmax
    k_final16<<<gRows, THREADS, 0, stream>>>(pool16, cnt, bfc, (float*)d_out, N);
}

// Round 4
// 306.018 us; speedup vs baseline: 1.1719x; 1.0225x over previous
//
#include <hip/hip_runtime.h>

#define THREADS 256
#define KC 32
#define B1 256          // partition blocks for P1/P2 (edge chunks)

typedef __attribute__((ext_vector_type(8))) short bf16x8;   // 8 bf16 (4 VGPR)
typedef __attribute__((ext_vector_type(4))) float f32x4;
typedef __attribute__((ext_vector_type(2))) unsigned int u32x2;

// ---- bf16 helpers ----
__device__ inline ushort f2bf(float v) {
    union { float f; unsigned u; } a; a.f = v;
    unsigned r = a.u + 0x7fff + ((a.u >> 16) & 1);
    return (ushort)(r >> 16);
}
__device__ inline unsigned pack2(float a, float b) {
    return (unsigned)f2bf(a) | ((unsigned)f2bf(b) << 16);
}
__device__ inline float bflo(unsigned v) {
    union { unsigned u; float f; } a; a.u = v << 16; return a.f;
}
__device__ inline float bfhi(unsigned v) {
    union { unsigned u; float f; } a; a.u = v & 0xffff0000u; return a.f;
}

// =================== CSR build: LDS counting sort, zero global atomics =======

__global__ void k_p1(const int* __restrict__ dst, int* __restrict__ pc,
                     int E, int NB, int chunk) {
    __shared__ int hist[512];
    int tid = threadIdx.x, blk = blockIdx.x;
    for (int i = tid; i < NB; i += THREADS) hist[i] = 0;
    __syncthreads();
    int e0 = blk * chunk;
    int e1 = e0 + chunk; if (e1 > E) e1 = E;
    for (int e = e0 + tid; e < e1; e += THREADS)
        atomicAdd(&hist[dst[e] >> 8], 1);
    __syncthreads();
    for (int i = tid; i < NB; i += THREADS) pc[i * B1 + blk] = hist[i];
}

__global__ void k_s1(int* __restrict__ pc, int* __restrict__ bsums, int total) {
    __shared__ int s[1024];
    int t = threadIdx.x;
    int idx = blockIdx.x * 1024 + t;
    int v = (idx < total) ? pc[idx] : 0;
    s[t] = v;
    __syncthreads();
    for (int o = 1; o < 1024; o <<= 1) {
        int x = (t >= (unsigned)o) ? s[t - o] : 0;
        __syncthreads();
        s[t] += x;
        __syncthreads();
    }
    if (idx < total) pc[idx] = s[t] - v;           // exclusive within block
    if (t == 1023) bsums[blockIdx.x] = s[1023];    // block total
}

__global__ void k_s2(int* __restrict__ bsums, int nb) {
    __shared__ int s[128];
    int t = threadIdx.x;
    int v = (t < nb) ? bsums[t] : 0;
    s[t] = v;
    __syncthreads();
    for (int o = 1; o < 128; o <<= 1) {
        int x = (t >= (unsigned)o) ? s[t - o] : 0;
        __syncthreads();
        s[t] += x;
        __syncthreads();
    }
    if (t < nb) bsums[t] = s[t] - v;
}

__global__ void k_p2(const int* __restrict__ src, const int* __restrict__ dst,
                     const int* __restrict__ pc, const int* __restrict__ bsx,
                     unsigned long long* __restrict__ part, int E, int NB, int chunk) {
    __shared__ int cur[512];
    int tid = threadIdx.x, blk = blockIdx.x;
    for (int i = tid; i < NB; i += THREADS) {
        int idx = i * B1 + blk;
        cur[i] = pc[idx] + bsx[idx >> 10];
    }
    __syncthreads();
    int e0 = blk * chunk;
    int e1 = e0 + chunk; if (e1 > E) e1 = E;
    for (int e = e0 + tid; e < e1; e += THREADS) {
        int d = dst[e], sv = src[e];
        int pos = atomicAdd(&cur[d >> 8], 1);      // LDS atomic
        part[pos] = ((unsigned long long)(unsigned)d << 32) | (unsigned)sv;
    }
}

__global__ void k_p3(const unsigned long long* __restrict__ part,
                     const int* __restrict__ pc, const int* __restrict__ bsx,
                     int* __restrict__ off, float* __restrict__ dinv,
                     int* __restrict__ csr, int E, int NB, int n) {
    __shared__ int hist[256];
    __shared__ int so[256];
    int b = blockIdx.x, t = threadIdx.x;
    int i0 = b * B1, i1 = (b + 1) * B1;
    int base = pc[i0] + bsx[i0 >> 10];
    int end  = (b + 1 < NB) ? (pc[i1] + bsx[i1 >> 10]) : E;
    hist[t] = 0;
    __syncthreads();
    for (int e = base + t; e < end; e += THREADS)
        atomicAdd(&hist[(int)(part[e] >> 32) & 255], 1);
    __syncthreads();
    int h = hist[t];
    so[t] = h;
    __syncthreads();
    for (int o = 1; o < 256; o <<= 1) {
        int x = (t >= (unsigned)o) ? so[t - o] : 0;
        __syncthreads();
        so[t] += x;
        __syncthreads();
    }
    int ex = so[t] - h;                            // exclusive within bucket
    int node = (b << 8) + t;
    if (node < n) {
        off[node]  = base + ex;
        dinv[node] = rsqrtf((float)h + 1.0f);
        if (node == n - 1) off[n] = E;
    }
    __syncthreads();
    so[t] = base + ex;                             // cursors
    __syncthreads();
    for (int e = base + t; e < end; e += THREADS) {
        unsigned long long p = part[e];
        int pos = atomicAdd(&so[(int)(p >> 32) & 255], 1);   // LDS atomic
        csr[pos] = (int)(p & 0xffffffffu);
    }
}

// =================== GEMM1 (fp32 X, dinv epilogue) + fused cnt role ========
__global__ __launch_bounds__(THREADS) void
k_g1(const float* __restrict__ X, const float* __restrict__ W,
     const float* __restrict__ dinv, ushort* __restrict__ C, int n, int fin,
     const int* __restrict__ dict, float* __restrict__ cnt, int nGemm, int nCnt) {
    int tid = threadIdx.x;
    if ((int)blockIdx.x >= nGemm) {
        int stride = nCnt * THREADS;
        for (int i = ((int)blockIdx.x - nGemm) * THREADS + tid; i < n; i += stride)
            atomicAdd(&cnt[dict[i]], 1.0f);
        return;
    }
    __shared__ float Xs[KC][68];
    __shared__ float Ws[KC][64];
    int r0  = blockIdx.x * 64;
    int tx4 = (tid & 15) * 4;
    int ty4 = (tid >> 4) * 4;
    int sxr = tid >> 2, sxk = (tid & 3) * 4;
    int swk = tid >> 4, swc = (tid & 15) * 4;
    int xrow = r0 + sxr; if (xrow >= n) xrow = n - 1;
    const float* xptr = X + (size_t)xrow * fin;
    float4 acc0 = {0,0,0,0}, acc1 = {0,0,0,0}, acc2 = {0,0,0,0}, acc3 = {0,0,0,0};
    for (int kc = 0; kc < fin; kc += KC) {
        float4 xa = *(const float4*)(xptr + kc + sxk);
        float4 xb = *(const float4*)(xptr + kc + 16 + sxk);
        float4 wa = *(const float4*)(W + (size_t)(kc + swk) * 64 + swc);
        float4 wb = *(const float4*)(W + (size_t)(kc + swk + 16) * 64 + swc);
        __syncthreads();
        Xs[sxk + 0][sxr] = xa.x; Xs[sxk + 1][sxr] = xa.y;
        Xs[sxk + 2][sxr] = xa.z; Xs[sxk + 3][sxr] = xa.w;
        Xs[16 + sxk + 0][sxr] = xb.x; Xs[16 + sxk + 1][sxr] = xb.y;
        Xs[16 + sxk + 2][sxr] = xb.z; Xs[16 + sxk + 3][sxr] = xb.w;
        *(float4*)&Ws[swk][swc]      = wa;
        *(float4*)&Ws[swk + 16][swc] = wb;
        __syncthreads();
        #pragma unroll 8
        for (int k = 0; k < KC; ++k) {
            float4 a = *(const float4*)&Xs[k][ty4];
            float4 b = *(const float4*)&Ws[k][tx4];
            acc0.x = fmaf(a.x, b.x, acc0.x); acc0.y = fmaf(a.x, b.y, acc0.y);
            acc0.z = fmaf(a.x, b.z, acc0.z); acc0.w = fmaf(a.x, b.w, acc0.w);
            acc1.x = fmaf(a.y, b.x, acc1.x); acc1.y = fmaf(a.y, b.y, acc1.y);
            acc1.z = fmaf(a.y, b.z, acc1.z); acc1.w = fmaf(a.y, b.w, acc1.w);
            acc2.x = fmaf(a.z, b.x, acc2.x); acc2.y = fmaf(a.z, b.y, acc2.y);
            acc2.z = fmaf(a.z, b.z, acc2.z); acc2.w = fmaf(a.z, b.w, acc2.w);
            acc3.x = fmaf(a.w, b.x, acc3.x); acc3.y = fmaf(a.w, b.y, acc3.y);
            acc3.z = fmaf(a.w, b.z, acc3.z); acc3.w = fmaf(a.w, b.w, acc3.w);
        }
    }
    int row = r0 + ty4;
    #pragma unroll
    for (int r = 0; r < 4; ++r) {
        if (row + r >= n) break;
        float dn = dinv[row + r];
        float4 a = r == 0 ? acc0 : r == 1 ? acc1 : r == 2 ? acc2 : acc3;
        ushort4 o;
        o.x = f2bf(a.x * dn); o.y = f2bf(a.y * dn);
        o.z = f2bf(a.z * dn); o.w = f2bf(a.w * dn);
        *(ushort4*)(C + (size_t)(row + r) * 64 + tx4) = o;
    }
}

// ---------- tiled GEMM (bf16 X): C' = (X@W)*dinv -> bf16 ----------
__global__ __launch_bounds__(THREADS) void
k_gemm_bf16(const ushort* __restrict__ X, const float* __restrict__ W,
            const float* __restrict__ dinv, ushort* __restrict__ C, int n, int fin) {
    __shared__ float Xs[KC][68];
    __shared__ float Ws[KC][64];
    int tid = threadIdx.x;
    int r0  = blockIdx.x * 64;
    int tx4 = (tid & 15) * 4;
    int ty4 = (tid >> 4) * 4;
    int sxr = tid >> 2, sk8 = (tid & 3) * 8;
    int swk = tid >> 4, swc = (tid & 15) * 4;
    int xrow = r0 + sxr; if (xrow >= n) xrow = n - 1;
    const ushort* xptr = X + (size_t)xrow * fin;
    float4 acc0 = {0,0,0,0}, acc1 = {0,0,0,0}, acc2 = {0,0,0,0}, acc3 = {0,0,0,0};
    for (int kc = 0; kc < fin; kc += KC) {
        uint4 xv = *(const uint4*)(xptr + kc + sk8);
        float4 wa = *(const float4*)(W + (size_t)(kc + swk) * 64 + swc);
        float4 wb = *(const float4*)(W + (size_t)(kc + swk + 16) * 64 + swc);
        __syncthreads();
        Xs[sk8 + 0][sxr] = bflo(xv.x); Xs[sk8 + 1][sxr] = bfhi(xv.x);
        Xs[sk8 + 2][sxr] = bflo(xv.y); Xs[sk8 + 3][sxr] = bfhi(xv.y);
        Xs[sk8 + 4][sxr] = bflo(xv.z); Xs[sk8 + 5][sxr] = bfhi(xv.z);
        Xs[sk8 + 6][sxr] = bflo(xv.w); Xs[sk8 + 7][sxr] = bfhi(xv.w);
        *(float4*)&Ws[swk][swc]      = wa;
        *(float4*)&Ws[swk + 16][swc] = wb;
        __syncthreads();
        #pragma unroll 8
        for (int k = 0; k < KC; ++k) {
            float4 a = *(const float4*)&Xs[k][ty4];
            float4 b = *(const float4*)&Ws[k][tx4];
            acc0.x = fmaf(a.x, b.x, acc0.x); acc0.y = fmaf(a.x, b.y, acc0.y);
            acc0.z = fmaf(a.x, b.z, acc0.z); acc0.w = fmaf(a.x, b.w, acc0.w);
            acc1.x = fmaf(a.y, b.x, acc1.x); acc1.y = fmaf(a.y, b.y, acc1.y);
            acc1.z = fmaf(a.y, b.z, acc1.z); acc1.w = fmaf(a.y, b.w, acc1.w);
            acc2.x = fmaf(a.z, b.x, acc2.x); acc2.y = fmaf(a.z, b.y, acc2.y);
            acc2.z = fmaf(a.z, b.z, acc2.z); acc2.w = fmaf(a.z, b.w, acc2.w);
            acc3.x = fmaf(a.w, b.x, acc3.x); acc3.y = fmaf(a.w, b.y, acc3.y);
            acc3.z = fmaf(a.w, b.z, acc3.z); acc3.w = fmaf(a.w, b.w, acc3.w);
        }
    }
    int row = r0 + ty4;
    #pragma unroll
    for (int r = 0; r < 4; ++r) {
        if (row + r >= n) break;
        float dn = dinv[row + r];
        float4 a = r == 0 ? acc0 : r == 1 ? acc1 : r == 2 ? acc2 : acc3;
        ushort4 o;
        o.x = f2bf(a.x * dn); o.y = f2bf(a.y * dn);
        o.z = f2bf(a.z * dn); o.w = f2bf(a.w * dn);
        *(ushort4*)(C + (size_t)(row + r) * 64 + tx4) = o;
    }
}

// =================== MFMA aggregation =======================================
// Wave = 16 dst nodes. D(16x64) = Ind(16x32) @ Hrows(32x64) per K-chunk.
// ds_read_b64_tr_b16 semantics (m156/m162): with per-lane addr base+lane*8,
// each 16-lane group G reads its 128B region [base+128G, +128) as a 4x16
// row-major block; lane l elem j = region[j*16 + (l&15)].
// B-fragment needed (mfma_f32_16x16x32_bf16): lane l holds B[k=8G+e][col=l&15].
//   -> store B[k][c] (c = 16t+ct) at byte offset
//        t*1024 + ((k>>2)&1)*512 + (k>>3)*128 + (k&3)*32 + ct*2
//   -> read pair for tile t: offsets t*1024 (e=0..3, k=8G+j) and
//      t*1024+512 (e=4..7, k=8G+4+j).
// Writer lane (g8=l>>3, q=l&7) stores row k=it*8+g8, cols [8q,8q+8) as one
// uint4 at ushort index  (q>>1)*512 + (g8>>2)*256 + it*64 + (g8&3)*16 + (q&1)*8.
__device__ inline void tr_mfma4(unsigned la, const bf16x8& a,
                                f32x4& o0, f32x4& o1, f32x4& o2, f32x4& o3) {
    u32x2 r0, r1, r2, r3, r4, r5, r6, r7;
    asm volatile(
        "s_waitcnt lgkmcnt(0)\n\t"
        "ds_read_b64_tr_b16 %0, %8 offset:0\n\t"
        "ds_read_b64_tr_b16 %1, %8 offset:512\n\t"
        "ds_read_b64_tr_b16 %2, %8 offset:1024\n\t"
        "ds_read_b64_tr_b16 %3, %8 offset:1536\n\t"
        "ds_read_b64_tr_b16 %4, %8 offset:2048\n\t"
        "ds_read_b64_tr_b16 %5, %8 offset:2560\n\t"
        "ds_read_b64_tr_b16 %6, %8 offset:3072\n\t"
        "ds_read_b64_tr_b16 %7, %8 offset:3584\n\t"
        "s_waitcnt lgkmcnt(0)"
        : "=&v"(r0), "=&v"(r1), "=&v"(r2), "=&v"(r3),
          "=&v"(r4), "=&v"(r5), "=&v"(r6), "=&v"(r7)
        : "v"(la) : "memory");
    __builtin_amdgcn_sched_barrier(0);       // keep MFMAs after the waitcnt
    union { u32x2 d[2]; bf16x8 v; } b0, b1, b2, b3;
    b0.d[0] = r0; b0.d[1] = r1; b1.d[0] = r2; b1.d[1] = r3;
    b2.d[0] = r4; b2.d[1] = r5; b3.d[0] = r6; b3.d[1] = r7;
    o0 = __builtin_amdgcn_mfma_f32_16x16x32_bf16(a, b0.v, o0, 0, 0, 0);
    o1 = __builtin_amdgcn_mfma_f32_16x16x32_bf16(a, b1.v, o1, 0, 0, 0);
    o2 = __builtin_amdgcn_mfma_f32_16x16x32_bf16(a, b2.v, o2, 0, 0, 0);
    o3 = __builtin_amdgcn_mfma_f32_16x16x32_bf16(a, b3.v, o3, 0, 0, 0);
}

// LAYER 1: relu(acc*dinv + b1) -> bf16 rows (coalesced via LDS repack)
// LAYER 2: relu(acc*dinv + b2) -> FC(64->16) -> atomicAdd pool16[dict[node]]
template<int LAYER>
__global__ __launch_bounds__(THREADS) void
k_agg(const ushort* __restrict__ H, const int* __restrict__ csr,
      const int* __restrict__ off, const float* __restrict__ dinv,
      const float* __restrict__ bias, ushort* __restrict__ outB,
      const float* __restrict__ Wfc, const int* __restrict__ dict,
      float* __restrict__ pool16, int n) {
    __shared__ ushort cbuf[4][2048];          // 4KB per wave, per-wave private
    __shared__ float wt[16 * 65];             // Wfc^T (LAYER2)
    int tid = threadIdx.x;
    if (LAYER == 2) {
        for (int i = tid; i < 64 * 16; i += THREADS) {
            int cc = i >> 4, r = i & 15;
            wt[r * 65 + cc] = Wfc[i];         // wt[r][cc] = Wfc[cc*16+r]
        }
        __syncthreads();                      // all threads reach this
    }
    int wslot = tid >> 6, lane = tid & 63;
    int gw = blockIdx.x * 4 + wslot;
    int n0 = gw << 4;
    if (n0 >= n) return;                      // after barrier: safe
    int G = lane >> 4, c16 = lane & 15;
    int g8 = lane >> 3, q = lane & 7;
    ushort* wbuf = &cbuf[wslot][0];
    unsigned lbase = (unsigned)(size_t)wbuf;  // LDS byte offset
    int vm = n - n0; if (vm > 16) vm = 16;
    int sA = 0, eA = 0;
    if (c16 < vm) { sA = off[n0 + c16]; eA = off[n0 + c16 + 1]; }
    int base0   = __shfl(sA, 0);
    int baseEnd = __shfl(eA, vm - 1);
    unsigned rng = (unsigned)(eA - sA);
    int sb0 = (q >> 1) * 512 + (g8 >> 2) * 256 + (g8 & 3) * 16 + (q & 1) * 8;
    unsigned la = lbase + (unsigned)lane * 8; // tr-read base (bytes)
    f32x4 acc0 = {0, 0, 0, 0}, acc1 = acc0, acc2 = acc0, acc3 = acc0;

    uint4 cur[4], nxt[4];
    #pragma unroll
    for (int it = 0; it < 4; ++it) {          // load first chunk
        uint4 v = {0, 0, 0, 0};
        int k = it * 8 + g8;
        if (base0 + k < baseEnd) {
            int e = csr[base0 + k];
            v = *(const uint4*)(H + ((size_t)e << 6) + q * 8);
        }
        cur[it] = v;
    }
    for (int base = base0; base < baseEnd; base += 32) {
        #pragma unroll
        for (int it = 0; it < 4; ++it) {      // prefetch next chunk
            uint4 v = {0, 0, 0, 0};
            int k = base + 32 + it * 8 + g8;
            if (k < baseEnd) {
                int e = csr[k];
                v = *(const uint4*)(H + ((size_t)e << 6) + q * 8);
            }
            nxt[it] = v;
        }
        #pragma unroll
        for (int it = 0; it < 4; ++it)        // stage current chunk
            *(uint4*)(wbuf + sb0 + it * 64) = cur[it];
        int kb = base - sA;                   // indicator: base+k in [sA,eA)
        bf16x8 a;
        #pragma unroll
        for (int e2 = 0; e2 < 8; ++e2)
            a[e2] = ((unsigned)(G * 8 + e2 + kb) < rng) ? (short)0x3F80 : (short)0;
        tr_mfma4(la, a, acc0, acc1, acc2, acc3);
        #pragma unroll
        for (int it = 0; it < 4; ++it) cur[it] = nxt[it];
    }
    {   // self-loop chunk: rows 0..15 = H[n0..n0+15], A = identity
        #pragma unroll
        for (int it = 0; it < 4; ++it) {
            uint4 v = {0, 0, 0, 0};
            int k = it * 8 + g8;
            if (it < 2 && k < vm)
                v = *(const uint4*)(H + ((size_t)(n0 + k) << 6) + q * 8);
            *(uint4*)(wbuf + sb0 + it * 64) = v;
        }
        bf16x8 a;
        #pragma unroll
        for (int e2 = 0; e2 < 8; ++e2)
            a[e2] = ((G * 8 + e2) == c16) ? (short)0x3F80 : (short)0;
        tr_mfma4(la, a, acc0, acc1, acc2, acc3);
    }
    // ---- epilogue: D layout col=lane&15 (=c16), row=G*4+r ----
    float* hrow = (float*)wbuf;               // 16x64 f32, aliases staging buf
    float bv0 = bias[c16], bv1 = bias[c16 + 16],
          bv2 = bias[c16 + 32], bv3 = bias[c16 + 48];
    #pragma unroll
    for (int r = 0; r < 4; ++r) {
        int rr = G * 4 + r;
        if (rr < vm) {
            float dn = dinv[n0 + rr];
            float v0 = fmaxf(acc0[r] * dn + bv0, 0.f);
            float v1 = fmaxf(acc1[r] * dn + bv1, 0.f);
            float v2 = fmaxf(acc2[r] * dn + bv2, 0.f);
            float v3 = fmaxf(acc3[r] * dn + bv3, 0.f);
            hrow[rr * 64 + c16]      = v0;
            hrow[rr * 64 + c16 + 16] = v1;
            hrow[rr * 64 + c16 + 32] = v2;
            hrow[rr * 64 + c16 + 48] = v3;
        }
    }
    asm volatile("" ::: "memory");            // order hrow writes vs reads
    if (LAYER == 1) {
        int prow = lane >> 2, pseg = lane & 3;   // 16 rows x 4 col-segments
        if (prow < vm) {
            const float* hp = hrow + prow * 64 + pseg * 16;
            float4 f0 = *(const float4*)(hp + 0);
            float4 f1 = *(const float4*)(hp + 4);
            float4 f2 = *(const float4*)(hp + 8);
            float4 f3 = *(const float4*)(hp + 12);
            uint4 o0, o1;
            o0.x = pack2(f0.x, f0.y); o0.y = pack2(f0.z, f0.w);
            o0.z = pack2(f1.x, f1.y); o0.w = pack2(f1.z, f1.w);
            o1.x = pack2(f2.x, f2.y); o1.y = pack2(f2.z, f2.w);
            o1.z = pack2(f3.x, f3.y); o1.w = pack2(f3.z, f3.w);
            ushort* op = outB + ((size_t)(n0 + prow) << 6) + pseg * 16;
            *(uint4*)(op)     = o0;
            *(uint4*)(op + 8) = o1;
        }
    } else {
        int r16 = c16;                        // class index; G = col quarter
        for (int m = 0; m < vm; ++m) {
            const float* hm = hrow + m * 64 + G * 16;
            const float* wr = wt + r16 * 65 + G * 16;
            float p = 0.f;
            #pragma unroll
            for (int i = 0; i < 16; ++i) p = fmaf(hm[i], wr[i], p);
            p += __shfl_xor(p, 16);
            p += __shfl_xor(p, 32);
            if (G == 0)
                atomicAdd(&pool16[(size_t)dict[n0 + m] * 16 + r16], p);
        }
    }
}

// ---------- mean + bias + log_softmax over 16 classes ----------
__global__ void k_final16(const float* __restrict__ pool16, const float* __restrict__ cnt,
                          const float* __restrict__ bfc, float* __restrict__ out, int n) {
    int tid = threadIdx.x;
    int nl = tid >> 4, lane = tid & 15;
    int node = blockIdx.x * 16 + nl;
    if (node >= n) return;
    float inv = 1.0f / fmaxf(cnt[node], 1.0f);
    float acc = pool16[(size_t)node * 16 + lane] * inv + bfc[lane];
    float m = acc;
    for (int o = 8; o; o >>= 1) m = fmaxf(m, __shfl_xor(m, o, 16));
    float ex = __expf(acc - m);
    float s = ex;
    for (int o = 8; o; o >>= 1) s += __shfl_xor(s, o, 16);
    out[(size_t)node * 16 + lane] = acc - m - __logf(s);
}

extern "C" void kernel_launch(void* const* d_in, const int* in_sizes, int n_in,
                              void* d_out, int out_size, void* d_ws, size_t ws_size,
                              hipStream_t stream) {
    const float* x    = (const float*)d_in[0];
    const int*   ei   = (const int*)d_in[1];
    const int*   dict = (const int*)d_in[2];
    const float* W1   = (const float*)d_in[3];
    const float* b1   = (const float*)d_in[4];
    const float* W2   = (const float*)d_in[5];
    const float* b2   = (const float*)d_in[6];
    const float* Wfc  = (const float*)d_in[7];
    const float* bfc  = (const float*)d_in[8];

    const int N  = in_sizes[2];          // 100000
    const int E  = in_sizes[1] / 2;      // 1600000
    const int IN = in_sizes[0] / N;      // 128
    const int* src = ei;
    const int* dst = ei + E;

    // workspace layout (~40 MB, identical to the proven round-1 plan)
    ushort* bufA = (ushort*)d_ws;                        // N*64 bf16
    ushort* bufB = bufA + (size_t)N * 64;                // N*64 bf16
    unsigned long long* part = (unsigned long long*)bufB;  // E u64 (alias bufB)
    float* dinv    = (float*)(bufB + (size_t)N * 64);    // N
    float* cnt     = dinv + N;                           // N
    int*   off     = (int*)(cnt + N);                    // N+1
    int*   pcounts = off + (N + 1);                      // NB*B1
    const int NB     = (N + 255) >> 8;                   // 391
    const int pcsize = NB * B1;                          // 100096
    int*   bsums   = pcounts + pcsize;                   // 128
    int*   csr     = bsums + 128;                        // E
    float* pool16  = (float*)(csr + E);                  // N*16

    const int gTile = (N + 63) / 64;                     // 1563
    const int gRows = (N + 15) / 16;                     // 6250
    const int nCnt  = 256;
    const int chunk = (E + B1 - 1) / B1;                 // 6250
    const int nS1   = (pcsize + 1023) >> 10;             // 98
    const int gAgg  = ((N + 15) / 16 + 3) / 4;           // 1563 (4 waves/block)

    hipMemsetAsync(cnt, 0, (size_t)N * sizeof(float), stream);
    hipMemsetAsync(pool16, 0, (size_t)N * 16 * sizeof(float), stream);

    // CSR build: LDS counting sort (no global atomics)
    k_p1<<<B1, THREADS, 0, stream>>>(dst, pcounts, E, NB, chunk);
    k_s1<<<nS1, 1024, 0, stream>>>(pcounts, bsums, pcsize);
    k_s2<<<1, 128, 0, stream>>>(bsums, nS1);
    k_p2<<<B1, THREADS, 0, stream>>>(src, dst, pcounts, bsums, part, E, NB, chunk);
    k_p3<<<NB, THREADS, 0, stream>>>(part, pcounts, bsums, off, dinv, csr, E, NB, N);

    // GEMM1 with dinv epilogue (+ dict cnt histogram hidden under it)
    k_g1<<<gTile + nCnt, THREADS, 0, stream>>>(x, W1, dinv, bufA, N, IN,
                                               dict, cnt, gTile, nCnt);

    // layer 1 MFMA aggregation: bufB = bf16(relu(dn*(sum+self)+b1))
    k_agg<1><<<gAgg, THREADS, 0, stream>>>(bufA, csr, off, dinv, b1, bufB,
                                           nullptr, nullptr, nullptr, N);

    // layer 2: bufA = bf16((bufB@W2)*dinv); MFMA agg -> relu -> FC -> pool16
    k_gemm_bf16<<<gTile, THREADS, 0, stream>>>(bufB, W2, dinv, bufA, N, 64);
    k_agg<2><<<gAgg, THREADS, 0, stream>>>(bufA, csr, off, dinv, b2, nullptr,
                                           Wfc, dict, pool16, N);

    // mean + bias + log_softmax
    k_final16<<<gRows, THREADS, 0, stream>>>(pool16, cnt, bfc, (float*)d_out, N);
}

// Round 7
// 298.808 us; speedup vs baseline: 1.2002x; 1.0241x over previous
//
#include <hip/hip_runtime.h>

#define THREADS 256
#define B1 256          // partition blocks for P1/P2 (edge chunks)

typedef __attribute__((ext_vector_type(8))) short bf16x8;   // 8 bf16 (4 VGPR)
typedef __attribute__((ext_vector_type(4))) float f32x4;
typedef __attribute__((ext_vector_type(2))) unsigned int u32x2;

// ---- bf16 helpers ----
__device__ inline ushort f2bf(float v) {
    union { float f; unsigned u; } a; a.f = v;
    unsigned r = a.u + 0x7fff + ((a.u >> 16) & 1);
    return (ushort)(r >> 16);
}
__device__ inline unsigned pack2(float a, float b) {
    return (unsigned)f2bf(a) | ((unsigned)f2bf(b) << 16);
}

// =================== CSR build (round-4 proven version) =====================

__global__ void k_p1(const int* __restrict__ dst, int* __restrict__ pc,
                     int E, int NB, int chunk) {
    __shared__ int hist[512];
    int tid = threadIdx.x, blk = blockIdx.x;
    for (int i = tid; i < NB; i += THREADS) hist[i] = 0;
    __syncthreads();
    int e0 = blk * chunk;
    int e1 = e0 + chunk; if (e1 > E) e1 = E;
    for (int e = e0 + tid; e < e1; e += THREADS)
        atomicAdd(&hist[dst[e] >> 8], 1);
    __syncthreads();
    for (int i = tid; i < NB; i += THREADS) pc[i * B1 + blk] = hist[i];
}

__global__ void k_s1(int* __restrict__ pc, int* __restrict__ bsums, int total) {
    __shared__ int s[1024];
    int t = threadIdx.x;
    int idx = blockIdx.x * 1024 + t;
    int v = (idx < total) ? pc[idx] : 0;
    s[t] = v;
    __syncthreads();
    for (int o = 1; o < 1024; o <<= 1) {
        int x = (t >= (unsigned)o) ? s[t - o] : 0;
        __syncthreads();
        s[t] += x;
        __syncthreads();
    }
    if (idx < total) pc[idx] = s[t] - v;           // exclusive within block
    if (t == 1023) bsums[blockIdx.x] = s[1023];    // block total
}

__global__ void k_s2(int* __restrict__ bsums, int nb) {
    __shared__ int s[128];
    int t = threadIdx.x;
    int v = (t < nb) ? bsums[t] : 0;
    s[t] = v;
    __syncthreads();
    for (int o = 1; o < 128; o <<= 1) {
        int x = (t >= (unsigned)o) ? s[t - o] : 0;
        __syncthreads();
        s[t] += x;
        __syncthreads();
    }
    if (t < nb) bsums[t] = s[t] - v;
}

__global__ void k_p2(const int* __restrict__ src, const int* __restrict__ dst,
                     const int* __restrict__ pc, const int* __restrict__ bsx,
                     unsigned long long* __restrict__ part, int E, int NB, int chunk) {
    __shared__ int cur[512];
    int tid = threadIdx.x, blk = blockIdx.x;
    for (int i = tid; i < NB; i += THREADS) {
        int idx = i * B1 + blk;
        cur[i] = pc[idx] + bsx[idx >> 10];
    }
    __syncthreads();
    int e0 = blk * chunk;
    int e1 = e0 + chunk; if (e1 > E) e1 = E;
    for (int e = e0 + tid; e < e1; e += THREADS) {
        int d = dst[e], sv = src[e];
        int pos = atomicAdd(&cur[d >> 8], 1);      // LDS atomic
        part[pos] = ((unsigned long long)(unsigned)d << 32) | (unsigned)sv;
    }
}

__global__ void k_p3(const unsigned long long* __restrict__ part,
                     const int* __restrict__ pc, const int* __restrict__ bsx,
                     int* __restrict__ off, float* __restrict__ dinv,
                     int* __restrict__ csr, int E, int NB, int n) {
    __shared__ int hist[256];
    __shared__ int so[256];
    int b = blockIdx.x, t = threadIdx.x;
    int i0 = b * B1, i1 = (b + 1) * B1;
    int base = pc[i0] + bsx[i0 >> 10];
    int end  = (b + 1 < NB) ? (pc[i1] + bsx[i1 >> 10]) : E;
    hist[t] = 0;
    __syncthreads();
    for (int e = base + t; e < end; e += THREADS)
        atomicAdd(&hist[(int)(part[e] >> 32) & 255], 1);
    __syncthreads();
    int h = hist[t];
    so[t] = h;
    __syncthreads();
    for (int o = 1; o < 256; o <<= 1) {
        int x = (t >= (unsigned)o) ? so[t - o] : 0;
        __syncthreads();
        so[t] += x;
        __syncthreads();
    }
    int ex = so[t] - h;                            // exclusive within bucket
    int node = (b << 8) + t;
    if (node < n) {
        off[node]  = base + ex;
        dinv[node] = rsqrtf((float)h + 1.0f);
        if (node == n - 1) off[n] = E;
    }
    __syncthreads();
    so[t] = base + ex;                             // cursors
    __syncthreads();
    for (int e = base + t; e < end; e += THREADS) {
        unsigned long long p = part[e];
        int pos = atomicAdd(&so[(int)(p >> 32) & 255], 1);   // LDS atomic
        csr[pos] = (int)(p & 0xffffffffu);
    }
}

// =================== MFMA dense GEMM: C = (X @ W) * dinv -> bf16 ===========
// No inline asm: W is staged ONCE into LDS directly in B-fragment order
//   wfrag[kk][t][lane][e]  (lane=(G,c16): holds B[k=kk*32+G*8+e][col=t*16+c16])
// so each lane reads its fragment with a plain 16B LDS load (ds_read_b128).
// Fragment conventions (HW-verified by round-4 k_agg refcheck):
//   A: lane l holds A[row=l&15][k=8*(l>>4)+e]
//   B: lane l holds B[k=8*(l>>4)+e][col=l&15]
//   D: lane l holds D[row=4*(l>>4)+r][col=l&15]
template<int KTILES, bool XF32>
__global__ __launch_bounds__(THREADS) void
k_mgemm(const float* __restrict__ Xf, const ushort* __restrict__ Xh,
        const float* __restrict__ W, const float* __restrict__ dinv,
        ushort* __restrict__ C, int n,
        const int* __restrict__ dict, float* __restrict__ cnt,
        int nGemm, int nCnt) {
    int tid = threadIdx.x;
    if ((int)blockIdx.x >= nGemm) {
        // ---- cnt role: dict histogram (hidden under the GEMM dispatch) ----
        int stride = nCnt * THREADS;
        for (int i = ((int)blockIdx.x - nGemm) * THREADS + tid; i < n; i += stride)
            atomicAdd(&cnt[dict[i]], 1.0f);
        return;
    }
    __shared__ ushort wfrag[KTILES * 2048];   // KTILES*4 tiles * 64 lanes * 8 bf16
    __shared__ float hrow[4][16 * 64];        // per-wave repack buffer (16 KB)
    const int FIN = KTILES * 32;
    for (int i = tid; i < FIN * 64; i += THREADS) {
        int k = i >> 6, c = i & 63;           // W[k][c], row-major [FIN][64]
        int kk = k >> 5, G = (k >> 3) & 3, e = k & 7;
        int t = c >> 4, c16 = c & 15;
        wfrag[(((kk * 4 + t) * 64) + G * 16 + c16) * 8 + e] = f2bf(W[i]);
    }
    __syncthreads();
    int wslot = tid >> 6, lane = tid & 63;
    int G = lane >> 4, c16 = lane & 15;
    int n0 = blockIdx.x * 64 + wslot * 16;
    int xrow = n0 + c16; if (xrow >= n) xrow = n - 1;
    const bf16x8* wf = (const bf16x8*)wfrag;
    f32x4 acc0 = {0, 0, 0, 0}, acc1 = acc0, acc2 = acc0, acc3 = acc0;
    #pragma unroll
    for (int kk = 0; kk < KTILES; ++kk) {
        bf16x8 a;
        if (XF32) {
            const float* xp = Xf + (size_t)xrow * FIN + kk * 32 + G * 8;
            float4 xa = *(const float4*)xp;
            float4 xb = *(const float4*)(xp + 4);
            a[0] = (short)f2bf(xa.x); a[1] = (short)f2bf(xa.y);
            a[2] = (short)f2bf(xa.z); a[3] = (short)f2bf(xa.w);
            a[4] = (short)f2bf(xb.x); a[5] = (short)f2bf(xb.y);
            a[6] = (short)f2bf(xb.z); a[7] = (short)f2bf(xb.w);
        } else {
            a = *(const bf16x8*)(Xh + (size_t)xrow * FIN + kk * 32 + G * 8);
        }
        bf16x8 b0 = wf[(kk * 4 + 0) * 64 + lane];
        bf16x8 b1 = wf[(kk * 4 + 1) * 64 + lane];
        bf16x8 b2 = wf[(kk * 4 + 2) * 64 + lane];
        bf16x8 b3 = wf[(kk * 4 + 3) * 64 + lane];
        acc0 = __builtin_amdgcn_mfma_f32_16x16x32_bf16(a, b0, acc0, 0, 0, 0);
        acc1 = __builtin_amdgcn_mfma_f32_16x16x32_bf16(a, b1, acc1, 0, 0, 0);
        acc2 = __builtin_amdgcn_mfma_f32_16x16x32_bf16(a, b2, acc2, 0, 0, 0);
        acc3 = __builtin_amdgcn_mfma_f32_16x16x32_bf16(a, b3, acc3, 0, 0, 0);
    }
    // ---- epilogue: D row=G*4+r, col=c16+16t; dinv scale; LDS repack ----
    int vm = n - n0; if (vm > 16) vm = 16;    // may be <=0 for tail waves
    float* hr = &hrow[wslot][0];
    #pragma unroll
    for (int r = 0; r < 4; ++r) {
        int rr = G * 4 + r;
        if (rr < vm) {
            float dn = dinv[n0 + rr];
            hr[rr * 64 + c16]      = acc0[r] * dn;
            hr[rr * 64 + c16 + 16] = acc1[r] * dn;
            hr[rr * 64 + c16 + 32] = acc2[r] * dn;
            hr[rr * 64 + c16 + 48] = acc3[r] * dn;
        }
    }
    asm volatile("" ::: "memory");            // same-wave LDS RAW ordering
    int prow = lane >> 2, pseg = lane & 3;    // 16 rows x 4 col-segments
    if (prow < vm) {
        const float* hp = hr + prow * 64 + pseg * 16;
        float4 f0 = *(const float4*)(hp + 0);
        float4 f1 = *(const float4*)(hp + 4);
        float4 f2 = *(const float4*)(hp + 8);
        float4 f3 = *(const float4*)(hp + 12);
        uint4 o0, o1;
        o0.x = pack2(f0.x, f0.y); o0.y = pack2(f0.z, f0.w);
        o0.z = pack2(f1.x, f1.y); o0.w = pack2(f1.z, f1.w);
        o1.x = pack2(f2.x, f2.y); o1.y = pack2(f2.z, f2.w);
        o1.z = pack2(f3.x, f3.y); o1.w = pack2(f3.z, f3.w);
        ushort* op = C + ((size_t)(n0 + prow) << 6) + pseg * 16;
        *(uint4*)(op)     = o0;
        *(uint4*)(op + 8) = o1;
    }
}

// =================== MFMA aggregation (round-4 proven, unchanged) ===========
__device__ inline void tr_mfma4(unsigned la, const bf16x8& a,
                                f32x4& o0, f32x4& o1, f32x4& o2, f32x4& o3) {
    u32x2 r0, r1, r2, r3, r4, r5, r6, r7;
    asm volatile(
        "s_waitcnt lgkmcnt(0)\n\t"
        "ds_read_b64_tr_b16 %0, %8 offset:0\n\t"
        "ds_read_b64_tr_b16 %1, %8 offset:512\n\t"
        "ds_read_b64_tr_b16 %2, %8 offset:1024\n\t"
        "ds_read_b64_tr_b16 %3, %8 offset:1536\n\t"
        "ds_read_b64_tr_b16 %4, %8 offset:2048\n\t"
        "ds_read_b64_tr_b16 %5, %8 offset:2560\n\t"
        "ds_read_b64_tr_b16 %6, %8 offset:3072\n\t"
        "ds_read_b64_tr_b16 %7, %8 offset:3584\n\t"
        "s_waitcnt lgkmcnt(0)"
        : "=&v"(r0), "=&v"(r1), "=&v"(r2), "=&v"(r3),
          "=&v"(r4), "=&v"(r5), "=&v"(r6), "=&v"(r7)
        : "v"(la) : "memory");
    __builtin_amdgcn_sched_barrier(0);       // keep MFMAs after the waitcnt
    union { u32x2 d[2]; bf16x8 v; } b0, b1, b2, b3;
    b0.d[0] = r0; b0.d[1] = r1; b1.d[0] = r2; b1.d[1] = r3;
    b2.d[0] = r4; b2.d[1] = r5; b3.d[0] = r6; b3.d[1] = r7;
    o0 = __builtin_amdgcn_mfma_f32_16x16x32_bf16(a, b0.v, o0, 0, 0, 0);
    o1 = __builtin_amdgcn_mfma_f32_16x16x32_bf16(a, b1.v, o1, 0, 0, 0);
    o2 = __builtin_amdgcn_mfma_f32_16x16x32_bf16(a, b2.v, o2, 0, 0, 0);
    o3 = __builtin_amdgcn_mfma_f32_16x16x32_bf16(a, b3.v, o3, 0, 0, 0);
}

// LAYER 1: relu(acc*dinv + b1) -> bf16 rows (coalesced via LDS repack)
// LAYER 2: relu(acc*dinv + b2) -> FC(64->16) -> atomicAdd pool16[dict[node]]
template<int LAYER>
__global__ __launch_bounds__(THREADS) void
k_agg(const ushort* __restrict__ H, const int* __restrict__ csr,
      const int* __restrict__ off, const float* __restrict__ dinv,
      const float* __restrict__ bias, ushort* __restrict__ outB,
      const float* __restrict__ Wfc, const int* __restrict__ dict,
      float* __restrict__ pool16, int n) {
    __shared__ ushort cbuf[4][2048];          // 4KB per wave, per-wave private
    __shared__ float wt[16 * 65];             // Wfc^T (LAYER2)
    int tid = threadIdx.x;
    if (LAYER == 2) {
        for (int i = tid; i < 64 * 16; i += THREADS) {
            int cc = i >> 4, r = i & 15;
            wt[r * 65 + cc] = Wfc[i];         // wt[r][cc] = Wfc[cc*16+r]
        }
        __syncthreads();                      // all threads reach this
    }
    int wslot = tid >> 6, lane = tid & 63;
    int gw = blockIdx.x * 4 + wslot;
    int n0 = gw << 4;
    if (n0 >= n) return;                      // after barrier: safe
    int G = lane >> 4, c16 = lane & 15;
    int g8 = lane >> 3, q = lane & 7;
    ushort* wbuf = &cbuf[wslot][0];
    unsigned lbase = (unsigned)(size_t)wbuf;  // LDS byte offset
    int vm = n - n0; if (vm > 16) vm = 16;
    int sA = 0, eA = 0;
    if (c16 < vm) { sA = off[n0 + c16]; eA = off[n0 + c16 + 1]; }
    int base0   = __shfl(sA, 0);
    int baseEnd = __shfl(eA, vm - 1);
    unsigned rng = (unsigned)(eA - sA);
    int sb0 = (q >> 1) * 512 + (g8 >> 2) * 256 + (g8 & 3) * 16 + (q & 1) * 8;
    unsigned la = lbase + (unsigned)lane * 8; // tr-read base (bytes)
    f32x4 acc0 = {0, 0, 0, 0}, acc1 = acc0, acc2 = acc0, acc3 = acc0;

    uint4 cur[4], nxt[4];
    #pragma unroll
    for (int it = 0; it < 4; ++it) {          // load first chunk
        uint4 v = {0, 0, 0, 0};
        int k = it * 8 + g8;
        if (base0 + k < baseEnd) {
            int e = csr[base0 + k];
            v = *(const uint4*)(H + ((size_t)e << 6) + q * 8);
        }
        cur[it] = v;
    }
    for (int base = base0; base < baseEnd; base += 32) {
        #pragma unroll
        for (int it = 0; it < 4; ++it) {      // prefetch next chunk
            uint4 v = {0, 0, 0, 0};
            int k = base + 32 + it * 8 + g8;
            if (k < baseEnd) {
                int e = csr[k];
                v = *(const uint4*)(H + ((size_t)e << 6) + q * 8);
            }
            nxt[it] = v;
        }
        #pragma unroll
        for (int it = 0; it < 4; ++it)        // stage current chunk
            *(uint4*)(wbuf + sb0 + it * 64) = cur[it];
        int kb = base - sA;                   // indicator: base+k in [sA,eA)
        bf16x8 a;
        #pragma unroll
        for (int e2 = 0; e2 < 8; ++e2)
            a[e2] = ((unsigned)(G * 8 + e2 + kb) < rng) ? (short)0x3F80 : (short)0;
        tr_mfma4(la, a, acc0, acc1, acc2, acc3);
        #pragma unroll
        for (int it = 0; it < 4; ++it) cur[it] = nxt[it];
    }
    {   // self-loop chunk: rows 0..15 = H[n0..n0+15], A = identity
        #pragma unroll
        for (int it = 0; it < 4; ++it) {
            uint4 v = {0, 0, 0, 0};
            int k = it * 8 + g8;
            if (it < 2 && k < vm)
                v = *(const uint4*)(H + ((size_t)(n0 + k) << 6) + q * 8);
            *(uint4*)(wbuf + sb0 + it * 64) = v;
        }
        bf16x8 a;
        #pragma unroll
        for (int e2 = 0; e2 < 8; ++e2)
            a[e2] = ((G * 8 + e2) == c16) ? (short)0x3F80 : (short)0;
        tr_mfma4(la, a, acc0, acc1, acc2, acc3);
    }
    // ---- epilogue: D layout col=lane&15 (=c16), row=G*4+r ----
    float* hrow = (float*)wbuf;               // 16x64 f32, aliases staging buf
    float bv0 = bias[c16], bv1 = bias[c16 + 16],
          bv2 = bias[c16 + 32], bv3 = bias[c16 + 48];
    #pragma unroll
    for (int r = 0; r < 4; ++r) {
        int rr = G * 4 + r;
        if (rr < vm) {
            float dn = dinv[n0 + rr];
            float v0 = fmaxf(acc0[r] * dn + bv0, 0.f);
            float v1 = fmaxf(acc1[r] * dn + bv1, 0.f);
            float v2 = fmaxf(acc2[r] * dn + bv2, 0.f);
            float v3 = fmaxf(acc3[r] * dn + bv3, 0.f);
            hrow[rr * 64 + c16]      = v0;
            hrow[rr * 64 + c16 + 16] = v1;
            hrow[rr * 64 + c16 + 32] = v2;
            hrow[rr * 64 + c16 + 48] = v3;
        }
    }
    asm volatile("" ::: "memory");            // order hrow writes vs reads
    if (LAYER == 1) {
        int prow = lane >> 2, pseg = lane & 3;   // 16 rows x 4 col-segments
        if (prow < vm) {
            const float* hp = hrow + prow * 64 + pseg * 16;
            float4 f0 = *(const float4*)(hp + 0);
            float4 f1 = *(const float4*)(hp + 4);
            float4 f2 = *(const float4*)(hp + 8);
            float4 f3 = *(const float4*)(hp + 12);
            uint4 o0, o1;
            o0.x = pack2(f0.x, f0.y); o0.y = pack2(f0.z, f0.w);
            o0.z = pack2(f1.x, f1.y); o0.w = pack2(f1.z, f1.w);
            o1.x = pack2(f2.x, f2.y); o1.y = pack2(f2.z, f2.w);
            o1.z = pack2(f3.x, f3.y); o1.w = pack2(f3.z, f3.w);
            ushort* op = outB + ((size_t)(n0 + prow) << 6) + pseg * 16;
            *(uint4*)(op)     = o0;
            *(uint4*)(op + 8) = o1;
        }
    } else {
        int r16 = c16;                        // class index; G = col quarter
        for (int m = 0; m < vm; ++m) {
            const float* hm = hrow + m * 64 + G * 16;
            const float* wr = wt + r16 * 65 + G * 16;
            float p = 0.f;
            #pragma unroll
            for (int i = 0; i < 16; ++i) p = fmaf(hm[i], wr[i], p);
            p += __shfl_xor(p, 16);
            p += __shfl_xor(p, 32);
            if (G == 0)
                atomicAdd(&pool16[(size_t)dict[n0 + m] * 16 + r16], p);
        }
    }
}

// ---------- mean + bias + log_softmax over 16 classes ----------
__global__ void k_final16(const float* __restrict__ pool16, const float* __restrict__ cnt,
                          const float* __restrict__ bfc, float* __restrict__ out, int n) {
    int tid = threadIdx.x;
    int nl = tid >> 4, lane = tid & 15;
    int node = blockIdx.x * 16 + nl;
    if (node >= n) return;
    float inv = 1.0f / fmaxf(cnt[node], 1.0f);
    float acc = pool16[(size_t)node * 16 + lane] * inv + bfc[lane];
    float m = acc;
    for (int o = 8; o; o >>= 1) m = fmaxf(m, __shfl_xor(m, o, 16));
    float ex = __expf(acc - m);
    float s = ex;
    for (int o = 8; o; o >>= 1) s += __shfl_xor(s, o, 16);
    out[(size_t)node * 16 + lane] = acc - m - __logf(s);
}

extern "C" void kernel_launch(void* const* d_in, const int* in_sizes, int n_in,
                              void* d_out, int out_size, void* d_ws, size_t ws_size,
                              hipStream_t stream) {
    const float* x    = (const float*)d_in[0];
    const int*   ei   = (const int*)d_in[1];
    const int*   dict = (const int*)d_in[2];
    const float* W1   = (const float*)d_in[3];
    const float* b1   = (const float*)d_in[4];
    const float* W2   = (const float*)d_in[5];
    const float* b2   = (const float*)d_in[6];
    const float* Wfc  = (const float*)d_in[7];
    const float* bfc  = (const float*)d_in[8];

    const int N  = in_sizes[2];          // 100000
    const int E  = in_sizes[1] / 2;      // 1600000
    const int IN = in_sizes[0] / N;      // 128
    const int* src = ei;
    const int* dst = ei + E;

    // workspace layout (~40 MB, round-4 proven plan)
    ushort* bufA = (ushort*)d_ws;                        // N*64 bf16
    ushort* bufB = bufA + (size_t)N * 64;                // N*64 bf16
    unsigned long long* part = (unsigned long long*)bufB;  // E u64 (alias bufB)
    float* dinv    = (float*)(bufB + (size_t)N * 64);    // N
    float* cnt     = dinv + N;                           // N
    int*   off     = (int*)(cnt + N);                    // N+1
    int*   pcounts = off + (N + 1);                      // NB*B1
    const int NB     = (N + 255) >> 8;                   // 391
    const int pcsize = NB * B1;                          // 100096
    int*   bsums   = pcounts + pcsize;                   // 128
    int*   csr     = bsums + 128;                        // E
    float* pool16  = (float*)(csr + E);                  // N*16

    const int gTile = (N + 63) / 64;                     // 1563
    const int gRows = (N + 15) / 16;                     // 6250
    const int nCnt  = 256;
    const int chunk = (E + B1 - 1) / B1;                 // 6250
    const int nS1   = (pcsize + 1023) >> 10;             // 98
    const int gAgg  = ((N + 15) / 16 + 3) / 4;           // 1563 (4 waves/block)

    hipMemsetAsync(cnt, 0, (size_t)N * sizeof(float), stream);
    hipMemsetAsync(pool16, 0, (size_t)N * 16 * sizeof(float), stream);

    // CSR build: LDS counting sort (no global atomics)
    k_p1<<<B1, THREADS, 0, stream>>>(dst, pcounts, E, NB, chunk);
    k_s1<<<nS1, 1024, 0, stream>>>(pcounts, bsums, pcsize);
    k_s2<<<1, 128, 0, stream>>>(bsums, nS1);
    k_p2<<<B1, THREADS, 0, stream>>>(src, dst, pcounts, bsums, part, E, NB, chunk);
    k_p3<<<NB, THREADS, 0, stream>>>(part, pcounts, bsums, off, dinv, csr, E, NB, N);

    // GEMM1 (MFMA, no asm): bufA = bf16((x@W1)*dinv)  (+ dict cnt role)
    k_mgemm<4, true><<<gTile + nCnt, THREADS, 0, stream>>>(
        x, nullptr, W1, dinv, bufA, N, dict, cnt, gTile, nCnt);

    // layer 1 MFMA aggregation: bufB = bf16(relu(dn*(sum+self)+b1))
    k_agg<1><<<gAgg, THREADS, 0, stream>>>(bufA, csr, off, dinv, b1, bufB,
                                           nullptr, nullptr, nullptr, N);

    // GEMM2 (MFMA, no asm): bufA = bf16((bufB@W2)*dinv); then agg2
    k_mgemm<2, false><<<gTile, THREADS, 0, stream>>>(
        nullptr, bufB, W2, dinv, bufA, N, nullptr, nullptr, gTile, 0);
    k_agg<2><<<gAgg, THREADS, 0, stream>>>(bufA, csr, off, dinv, b2, nullptr,
                                           Wfc, dict, pool16, N);

    // mean + bias + log_softmax
    k_final16<<<gRows, THREADS, 0, stream>>>(pool16, cnt, bfc, (float*)d_out, N);
}